// Round 17
// baseline (3190.361 us; speedup 1.0000x reference)
//
#include <hip/hip_runtime.h>
#include <stdint.h>
#include <math.h>

#define KNB 40
static constexpr int NB = 16;   // batch

using short8 = __attribute__((ext_vector_type(8))) short;
using f32x4  = __attribute__((ext_vector_type(4))) float;

// ---------------- workspace layout (bytes), total ~178.4 MB ----------------
static constexpr size_t OFF_W4  = 0;            // 4-batch W chunk, bf16 tiled = 47,185,920 B
static constexpr size_t OFF_Hb  = 47185920;     // H bf16 tiled = 94,371,840 B
static constexpr size_t OFF_FA  = 141557760;    // fout ping (f32, 2,359,296)
static constexpr size_t OFF_FB  = 150994944;    // fout pong
static constexpr size_t OFF_FT  = 160432128;    // featsT f32 [b][n][C] (9,437,184 B)
static constexpr size_t OFF_XA  = 169869312;    // lc ping (16*1024*3 f32)
static constexpr size_t OFF_XB  = 170065920;
static constexpr size_t OFF_FPS = 170262528;    // 16*1024 int
static constexpr size_t OFF_KNN = 170328064;    // 16*1024*40 int
static constexpr size_t OFF_W1H = 172949504;    // w1 bf16 tiled (max 663,552 elems)
static constexpr size_t OFF_W2H = 175603712;
static constexpr size_t OFF_SUM = 178257920;    // 8*1152 f32 (split accumulators)
static constexpr size_t OFF_SQ  = 178294784;    // 8*1152 f32
static constexpr size_t OFF_SC1 = 178331648;    // 1152 f32
static constexpr size_t OFF_SH1 = 178336256;
static constexpr size_t OFF_SC2 = 178340864;
static constexpr size_t OFF_SH2 = 178345472;
static constexpr size_t OFF_DST = 178350080;    // 2 doubles
static constexpr size_t OFF_INV = 178350096;    // 1 f32

// ---------------- bf16 helpers (manual, RNE) ----------------
__device__ static inline float bf2f(uint16_t h){ return __uint_as_float(((uint32_t)h) << 16); }
__device__ static inline uint16_t f2bf(float f){
  uint32_t u = __float_as_uint(f);
  uint32_t r = u + 0x7fffu + ((u >> 16) & 1u);
  return (uint16_t)(r >> 16);
}

// async global->LDS, 16B per lane: lds dest = wave-uniform base + lane*16
__device__ static inline void gload_lds16(const void* g, void* l){
  __builtin_amdgcn_global_load_lds((const __attribute__((address_space(1))) uint32_t*)g,
                                   (__attribute__((address_space(3))) uint32_t*)l, 16, 0, 0);
}

// ---------------- JAX Threefry-2x32 (exact) ----------------
__host__ __device__ static inline uint32_t rotl32(uint32_t v, int d){ return (v<<d)|(v>>(32-d)); }
#define TF_RND(r) { x0 += x1; x1 = rotl32(x1,(r)); x1 ^= x0; }
__host__ __device__ static inline void tf2x32(uint32_t k0, uint32_t k1, uint32_t& x0, uint32_t& x1){
  uint32_t ks2 = k0 ^ k1 ^ 0x1BD11BDAu;
  x0 += k0; x1 += k1;
  TF_RND(13) TF_RND(15) TF_RND(26) TF_RND(6)   x0 += k1;  x1 += ks2 + 1u;
  TF_RND(17) TF_RND(29) TF_RND(16) TF_RND(24)  x0 += ks2; x1 += k0 + 2u;
  TF_RND(13) TF_RND(15) TF_RND(26) TF_RND(6)   x0 += k0;  x1 += k1 + 3u;
  TF_RND(17) TF_RND(29) TF_RND(16) TF_RND(24)  x0 += k1;  x1 += ks2 + 4u;
  TF_RND(13) TF_RND(15) TF_RND(26) TF_RND(6)   x0 += ks2; x1 += k0 + 5u;
}

__device__ static inline float freq_of(int t, int f){
  return exp2f(-((float)t / (float)f) * 9.965784284662087f);  // 1000^(-t/f)
}

// ---------------- embed ----------------
__global__ __launch_bounds__(256) void k_embed(const float* __restrict__ x,
                                               const float* __restrict__ w,
                                               float* __restrict__ out){
  __shared__ float sw[216];
  int t = threadIdx.x;
  if (t < 216) sw[t] = w[t];
  __syncthreads();
  int gid = blockIdx.x*256 + t;
  int n = gid & 2047, b = gid >> 11;
  float x0 = x[((size_t)b*3+0)*2048 + n];
  float x1 = x[((size_t)b*3+1)*2048 + n];
  float x2 = x[((size_t)b*3+2)*2048 + n];
  #pragma unroll 4
  for (int o = 0; o < 72; ++o){
    float v = sw[o*3]*x0 + sw[o*3+1]*x1 + sw[o*3+2]*x2;
    out[((size_t)b*72 + o)*2048 + n] = v;
  }
}

__global__ __launch_bounds__(256) void k_chan_stats_f32(const float* __restrict__ in, int C, int M,
                                                        float* __restrict__ SUMf, float* __restrict__ SQf){
  int c = blockIdx.x, b = blockIdx.y;
  const float* p = in + ((size_t)b*C + c)*M;
  float s = 0.f, s2 = 0.f;
  for (int m = threadIdx.x; m < M; m += 256){ float v = p[m]; s += v; s2 += v*v; }
  __shared__ float sa[256], sb[256];
  int t = threadIdx.x;
  sa[t] = s; sb[t] = s2; __syncthreads();
  for (int o = 128; o > 0; o >>= 1){
    if (t < o){ sa[t] += sa[t+o]; sb[t] += sb[t+o]; }
    __syncthreads();
  }
  if (t == 0){ atomicAdd(&SUMf[c], sa[0]); atomicAdd(&SQf[c], sb[0]); }
}

// finalize from 8-way split accumulators
__global__ void k_bn_finalize8(const float* __restrict__ SUMf, const float* __restrict__ SQf,
                               int C, double Mn, const float* __restrict__ gamma,
                               const float* __restrict__ beta, float* __restrict__ scale,
                               float* __restrict__ shift){
  int c = blockIdx.x*blockDim.x + threadIdx.x;
  if (c >= C) return;
  float s = 0.f, q = 0.f;
  #pragma unroll
  for (int k = 0; k < 8; ++k){ s += SUMf[k*1152 + c]; q += SQf[k*1152 + c]; }
  double mean = (double)s / Mn;
  double var = (double)q / Mn - mean*mean;
  if (var < 0.0) var = 0.0;
  float sc = gamma[c] / sqrtf((float)var + 1e-5f);
  scale[c] = sc;
  shift[c] = beta[c] - (float)mean * sc;
}

__global__ __launch_bounds__(256) void k_bn_apply(float* __restrict__ buf,
                                                  const float* __restrict__ scale,
                                                  const float* __restrict__ shift,
                                                  int C, int M, long long total){
  long long idx = (long long)blockIdx.x*256 + threadIdx.x;
  if (idx >= total) return;
  int c = (int)((idx / M) % C);
  float v = buf[idx]*scale[c] + shift[c];
  buf[idx] = fmaxf(v, 0.f);
}

// feats [b][C][n] -> featsT [b][n][C], LDS-tiled (both sides coalesced)
__global__ __launch_bounds__(256) void k_transpose(const float* __restrict__ in,
                                                   float* __restrict__ out, int C, int ncur){
  __shared__ float tile[64][65];
  int b = blockIdx.z;
  int n0 = blockIdx.x * 64;
  int c0 = blockIdx.y * 64;
  int tx = threadIdx.x & 63, ty = threadIdx.x >> 6;
  #pragma unroll
  for (int r = 0; r < 64; r += 4){
    int c = c0 + r + ty;
    if (c < C) tile[r + ty][tx] = in[((size_t)b*C + c)*ncur + n0 + tx];
  }
  __syncthreads();
  #pragma unroll
  for (int r = 0; r < 64; r += 4){
    int n = n0 + r + ty;
    int c = c0 + tx;
    if (c < C) out[((size_t)b*ncur + n)*C + c] = tile[tx][r + ty];
  }
}

// weights f32 [Cout][Cin] -> bf16 MFMA-fragment tiling [r/16][k/8][16][8]
__global__ __launch_bounds__(256) void k_wconv_tiled(const float* __restrict__ w,
                                                     uint16_t* __restrict__ hi,
                                                     int Cout, int Cin){
  int i = blockIdx.x*256 + threadIdx.x;
  if (i >= Cout*Cin) return;
  int row = i / Cin, k = i - row*Cin;
  size_t o = (((size_t)(row>>4)*(Cin>>3) + (k>>3))*16 + (row&15))*8 + (k&7);
  hi[o] = f2bf(w[i]);
}

// ---------------- sampling / knn ----------------
__global__ __launch_bounds__(256) void k_fps(const float* __restrict__ xyz, float* __restrict__ lc,
                                             int* __restrict__ fps, int ncur, int g,
                                             uint32_t ka, uint32_t kb){
  int m = blockIdx.x*256 + threadIdx.x;
  int total = NB * g;
  if (m >= total) return;
  uint32_t x0 = 0u, x1 = (uint32_t)m;
  tf2x32(ka, kb, x0, x1);
  uint32_t v = x0 ^ x1;
  int idx = (int)(v & (uint32_t)(ncur - 1));
  fps[m] = idx;
  int b = m / g;
  const float* s = xyz + ((size_t)b*ncur + idx)*3;
  float* d = lc + (size_t)m*3;
  d[0] = s[0]; d[1] = s[1]; d[2] = s[2];
}

// final xyz output: full 4-stage index composition, reads ONLY xyz0 (no ws deps)
__global__ __launch_bounds__(256) void k_final_xyz(const float* __restrict__ xyz0,
                                                   float* __restrict__ out,
                                                   uint32_t ka0, uint32_t kb0,
                                                   uint32_t ka1, uint32_t kb1,
                                                   uint32_t ka2, uint32_t kb2,
                                                   uint32_t ka3, uint32_t kb3){
  int m = blockIdx.x*256 + threadIdx.x;     // b*128 + j
  if (m >= 2048) return;
  int b = m >> 7;
  uint32_t x0, x1;
  x0 = 0u; x1 = (uint32_t)m;        tf2x32(ka3, kb3, x0, x1);
  uint32_t i3 = (x0 ^ x1) & 255u;   // stage-3 input has ncur=256
  x0 = 0u; x1 = (uint32_t)b*256u + i3;  tf2x32(ka2, kb2, x0, x1);
  uint32_t i2 = (x0 ^ x1) & 511u;
  x0 = 0u; x1 = (uint32_t)b*512u + i2;  tf2x32(ka1, kb1, x0, x1);
  uint32_t i1 = (x0 ^ x1) & 1023u;
  x0 = 0u; x1 = (uint32_t)b*1024u + i1; tf2x32(ka0, kb0, x0, x1);
  uint32_t i0 = (x0 ^ x1) & 2047u;
  const float* s = xyz0 + ((size_t)b*2048 + i0)*3;
  out[(size_t)m*3+0] = s[0];
  out[(size_t)m*3+1] = s[1];
  out[(size_t)m*3+2] = s[2];
}

// knn: 4 waves per block, each wave handles one row; per-wave body is the
// EXACT frozen R3 text (load/d2/pack loop and selection untouched).
template<int CNT>
__global__ __launch_bounds__(256) void k_knn(const float* __restrict__ xyz,
                                             const float* __restrict__ lc,
                                             int* __restrict__ knn, int ncur, int g){
  int row = blockIdx.x*4 + (threadIdx.x >> 6);   // b*g + j
  int b = row / g;
  int lane = threadIdx.x & 63;
  float lx = lc[row*3+0], ly = lc[row*3+1], lz = lc[row*3+2];
  float ln = lx*lx + ly*ly + lz*lz;
  const float* xb = xyz + (size_t)b*ncur*3;
  unsigned long long pk[CNT];
  #pragma unroll
  for (int t = 0; t < CNT; ++t){
    int n = lane + 64*t;
    float px = xb[n*3+0], py = xb[n*3+1], pz = xb[n*3+2];
    float dot = lx*px + ly*py + lz*pz;
    float pn = px*px + py*py + pz*pz;
    float d2 = -2.0f*dot + ln + pn;
    unsigned u = __float_as_uint(d2);
    if (u == 0x80000000u) u = 0u;
    unsigned su = (u & 0x80000000u) ? ~u : (u | 0x80000000u);
    pk[t] = ((unsigned long long)su << 32) | (unsigned)n;
  }
  for (int it = 0; it < KNB; ++it){
    unsigned long long m = ~0ull;
    #pragma unroll
    for (int t = 0; t < CNT; ++t) m = (pk[t] < m) ? pk[t] : m;
    #pragma unroll
    for (int s = 1; s < 64; s <<= 1){
      unsigned long long o = __shfl_xor(m, s, 64);
      m = (o < m) ? o : m;
    }
    if (lane == 0) knn[(size_t)row*KNB + it] = (int)(unsigned)(m & 0xffffffffu);
    #pragma unroll
    for (int t = 0; t < CNT; ++t) if (pk[t] == m) pk[t] = ~0ull;
  }
}

__global__ __launch_bounds__(256) void k_diff_stats(const float* __restrict__ xyz,
                                                    const float* __restrict__ lc,
                                                    const int* __restrict__ knn,
                                                    int ncur, int g, double* __restrict__ out){
  long long gid = (long long)blockIdx.x*256 + threadIdx.x;
  long long total = (long long)NB*g*KNB;
  double s = 0.0, s2 = 0.0;
  if (gid < total){
    long long jj = gid / KNB;
    int nn = knn[gid];
    const float* p = xyz + ((size_t)(jj/g)*ncur + nn)*3;
    const float* c = lc + (size_t)jj*3;
    #pragma unroll
    for (int a = 0; a < 3; ++a){ float df = p[a] - c[a]; double d = (double)df; s += d; s2 += d*d; }
  }
  __shared__ double sa[256], sb[256];
  int t = threadIdx.x;
  sa[t] = s; sb[t] = s2; __syncthreads();
  for (int o = 128; o > 0; o >>= 1){
    if (t < o){ sa[t] += sa[t+o]; sb[t] += sb[t+o]; }
    __syncthreads();
  }
  if (t == 0){ atomicAdd(&out[0], sa[0]); atomicAdd(&out[1], sb[0]); }
}

__global__ void k_scalar_fin(const double* __restrict__ dst, double Mn, float* __restrict__ inv_std){
  double s = dst[0], s2 = dst[1];
  double mean = s / Mn;
  double var = (s2 - s*mean) / (Mn - 1.0);     // ddof=1
  if (var < 0.0) var = 0.0;
  float stdv = sqrtf((float)var);
  *inv_std = 1.0f / (stdv + 1e-5f);
}

// ---------------- build W chunk, bf16 fragment tiling, 8ch/thread, coalesced 16B stores ----------------
__global__ __launch_bounds__(256) void k_build_w8(const float* __restrict__ featsT,
                                                  const float* __restrict__ xyz,
                                                  const float* __restrict__ lc,
                                                  const int* __restrict__ fps,
                                                  const int* __restrict__ knn,
                                                  const float* __restrict__ inv_std,
                                                  uint16_t* __restrict__ W4,
                                                  int C, int g, int ncur, int f, int b0){
  long long idx = (long long)blockIdx.x*256 + threadIdx.x;
  int C2 = 6*f;
  int C8 = C2 >> 3;
  int M = g*KNB;
  int M16 = M >> 4;
  long long total = 4LL*M16*C8*16;
  if (idx >= total) return;
  int n_in = (int)(idx & 15);
  long long r2 = idx >> 4;
  int c8 = (int)(r2 % C8);
  long long r3 = r2 / C8;
  int n16 = (int)(r3 % M16);
  int bl = (int)(r3 / M16);
  int b = b0 + bl;
  int n = n16*16 + n_in;
  int j = n / KNB;
  int k = n - j*KNB;
  int nn = knn[((size_t)(b*g+j))*KNB + k];
  float is = *inv_std;
  int ch0 = c8*8;
  int axis = ch0 / (2*f);
  float diff = xyz[((size_t)b*ncur + nn)*3 + axis] - lc[((size_t)(b*g+j))*3 + axis];
  float base = 100.0f * (diff * is);
  bool isCtr = (ch0 >= C);
  int src = isCtr ? fps[b*g+j] : nn;
  const float* fsrc = featsT + ((size_t)b*ncur + src)*C + (isCtr ? (ch0 - C) : ch0);
  int r0_ = ch0 % (2*f);
  bool sinb = (r0_ < f);        // uniform within 8-block (f % 8 == 0)
  int t0 = sinb ? r0_ : (r0_ - f);
  short8 sv;
  #pragma unroll
  for (int e = 0; e < 8; ++e){
    float fr = freq_of(t0 + e, f);
    float arg = base * fr;
    float pe = sinb ? __sinf(arg) : __cosf(arg);
    sv[e] = (short)f2bf(fsrc[e] + pe);
  }
  size_t woff = (((size_t)bl*M16 + n16)*(size_t)C8 + c8)*128 + (size_t)n_in*8;
  *(short8*)(W4 + woff) = sv;
}

// H in-place: relu(bn1(H)), bf16 tiled, 4 elems/thread
__global__ __launch_bounds__(256) void k_bn1_relu4(uint16_t* __restrict__ H,
                                                   const float* __restrict__ sc, const float* __restrict__ sh,
                                                   int K8, long long total4){
  long long i = (long long)blockIdx.x*256 + threadIdx.x;
  if (i >= total4) return;
  long long e0 = i << 2;
  int cb = (int)((e0 >> 7) % K8)*8 + (int)(e0 & 7);
  uint2 v = *(uint2*)(H + e0);
  uint16_t h0 = (uint16_t)(v.x & 0xffff), h1 = (uint16_t)(v.x >> 16);
  uint16_t h2 = (uint16_t)(v.y & 0xffff), h3 = (uint16_t)(v.y >> 16);
  float r0 = fmaxf(bf2f(h0)*sc[cb+0] + sh[cb+0], 0.f);
  float r1 = fmaxf(bf2f(h1)*sc[cb+1] + sh[cb+1], 0.f);
  float r2 = fmaxf(bf2f(h2)*sc[cb+2] + sh[cb+2], 0.f);
  float r3 = fmaxf(bf2f(h3)*sc[cb+3] + sh[cb+3], 0.f);
  uint2 o;
  o.x = (uint32_t)f2bf(r0) | ((uint32_t)f2bf(r1) << 16);
  o.y = (uint32_t)f2bf(r2) | ((uint32_t)f2bf(r3) << 16);
  *(uint2*)(H + e0) = o;
}

// ---------------- MFMA GEMM (R14 structure), async B staging, XCD swizzle ----------------
// A tiled [r/16][k/8][16][8]; B tiled [z][n/16][k/8][16][8]
// Per 32-k step: async-stage next B-tile, ds_read current, MFMA, barrier.
// SS: n-block stride multiplier (MODE 1 subsampled stats; 1 otherwise)
// MODE 0 (NSUB=1): gemm1 -> store H tiled + bias + BN stats   (epilogue LDS elided)
// MODE 1 (NSUB=1): gemm2 stats pass (subsampled)               (epilogue LDS elided)
// MODE 2 (NSUB=5): gemm2 final: LDS-staged epilogue (fast sincos), maxpool -> fout
template<int MODE, int NSUB>
__global__ __launch_bounds__(256) void k_mfma_tile(
    const uint16_t* __restrict__ Ahi,
    const uint16_t* __restrict__ Bmat,
    const float* __restrict__ bias,
    uint16_t* __restrict__ Hout,
    float* __restrict__ SUMf, float* __restrict__ SQf,
    const float* __restrict__ sc2, const float* __restrict__ sh2,
    const float* __restrict__ featsT,
    const float* __restrict__ xyz, const float* __restrict__ lc,
    const int* __restrict__ fps, const int* __restrict__ knn,
    const float* __restrict__ inv_std, float* __restrict__ fout,
    int Cout, int Cin, int M, int b0, int C, int g, int ncur, int f, int RY, int SS)
{
  __shared__ unsigned lmax[(MODE==2)?1152:4];       // [128 ch][9 stride] (MODE 2 only)
  __shared__ uint16_t c2t[(MODE==2)?(64*130):4];    // [64 col][130 ch] bf16 (MODE 2 only)
  __shared__ float dls[(MODE==2)?64:1][3];          // per-col 100*(diff*is) (MODE 2 only)
  __shared__ int nnls[(MODE==2)?64:1], ctrls[(MODE==2)?64:1];
  __shared__ uint16_t Bst[2][2048];                 // double-buffered 4KB B staging
  int bz = blockIdx.z; int b = b0 + bz;
  int lin = blockIdx.x;
  int GXW = (int)gridDim.x / (8*RY);
  int xcd = lin & 7;
  int slot = lin >> 3;
  int sdiv = slot / RY;
  int bx = xcd*GXW + sdiv;
  int ry = slot - sdiv*RY;
  int r0 = ry * 128;
  int tid = threadIdx.x;
  int w = tid >> 6, l = tid & 63;
  int lr = l & 15, kg = l >> 4;
  int rw = r0 + w*32;
  const short8 zf = (short8){0,0,0,0,0,0,0,0};

  if (MODE == 2){
    for (int e = tid; e < 1152; e += 256) lmax[e] = 0u;
    __syncthreads();
  }
  float sacc[2][4] = {{0.f,0.f,0.f,0.f},{0.f,0.f,0.f,0.f}};
  float qacc[2][4] = {{0.f,0.f,0.f,0.f},{0.f,0.f,0.f,0.f}};
  float is = (MODE == 2) ? *inv_std : 0.f;

  int K8 = Cin >> 3;
  int T = (Cin + 31) >> 5;    // 32-k steps
  int rw16 = rw >> 4;
  const size_t aoff0 = ((size_t)(rw16+0)*K8)*128 + (size_t)lr*8;
  const size_t aoff1 = ((size_t)(rw16+1)*K8)*128 + (size_t)lr*8;
  bool rv0 = (rw + lr) < Cout, rv1 = (rw + 16 + lr) < Cout;
  const uint16_t* Bbat = Bmat + (size_t)bz*(M>>4)*(size_t)K8*128;

  for (int sub = 0; sub < NSUB; ++sub){
    int n0 = (bx*NSUB + sub)*64*SS;
    int nb0 = n0 >> 4;
    const uint16_t* srcW = Bbat + ((size_t)(nb0 + w)*K8)*128 + (size_t)l*8;
    f32x4 acc[2][4];
    #pragma unroll
    for (int i = 0; i < 2; ++i)
      #pragma unroll
      for (int j = 0; j < 4; ++j) acc[i][j] = (f32x4){0.f,0.f,0.f,0.f};

    // prologue: async-stage step 0 into buf0; A prefetch step 0 (registers)
    gload_lds16(srcW, &Bst[0][w*512]);
    short8 ahc[2];
    {
      int kb = kg;
      bool kv = kb < K8;
      ahc[0] = (kv && rv0) ? *(const short8*)(Ahi + aoff0 + (size_t)kb*128) : zf;
      ahc[1] = (kv && rv1) ? *(const short8*)(Ahi + aoff1 + (size_t)kb*128) : zf;
    }
    __syncthreads();

    for (int t = 0; t < T; ++t){
      int buf = t & 1;
      bool more = (t + 1) < T;
      if (more) gload_lds16(srcW + (size_t)(t+1)*512, &Bst[buf^1][w*512]);
      short8 ahn[2];
      int kbn = (t+1)*4 + kg;
      bool kvn = kbn < K8;
      if (more){
        ahn[0] = (kvn && rv0) ? *(const short8*)(Ahi + aoff0 + (size_t)kbn*128) : zf;
        ahn[1] = (kvn && rv1) ? *(const short8*)(Ahi + aoff1 + (size_t)kbn*128) : zf;
      }
      short8 bvc[4];
      int kb = t*4 + kg;
      bool kv = kb < K8;
      #pragma unroll
      for (int nf = 0; nf < 4; ++nf){
        short8 bv = *(const short8*)(&Bst[buf][nf*512 + l*8]);
        bvc[nf] = kv ? bv : zf;
      }
      #pragma unroll
      for (int nf = 0; nf < 4; ++nf){
        acc[0][nf] = __builtin_amdgcn_mfma_f32_16x16x32_bf16(ahc[0], bvc[nf], acc[0][nf], 0, 0, 0);
        acc[1][nf] = __builtin_amdgcn_mfma_f32_16x16x32_bf16(ahc[1], bvc[nf], acc[1][nf], 0, 0, 0);
      }
      if (more){ ahc[0] = ahn[0]; ahc[1] = ahn[1]; }
      __syncthreads();
    }

    if (MODE == 0 || MODE == 1){
      int K8h = Cout >> 3;
      #pragma unroll
      for (int rf = 0; rf < 2; ++rf){
        int chbase = rw + rf*16 + kg*4;
        bool cv = chbase < Cout;
        float bz4[4];
        #pragma unroll
        for (int r = 0; r < 4; ++r) bz4[r] = cv ? bias[chbase + r] : 0.f;
        #pragma unroll
        for (int nf = 0; nf < 4; ++nf){
          float v0 = acc[rf][nf][0] + bz4[0];
          float v1 = acc[rf][nf][1] + bz4[1];
          float v2 = acc[rf][nf][2] + bz4[2];
          float v3 = acc[rf][nf][3] + bz4[3];
          if (MODE == 0 && cv){
            ushort4 st = make_ushort4(f2bf(v0), f2bf(v1), f2bf(v2), f2bf(v3));
            size_t hoff = ((((size_t)b*(M>>4) + nb0 + nf)*K8h + (chbase>>3))*16 + lr)*8 + (chbase&7);
            *(ushort4*)(Hout + hoff) = st;
          }
          sacc[rf][0]+=v0; qacc[rf][0]+=v0*v0;
          sacc[rf][1]+=v1; qacc[rf][1]+=v1*v1;
          sacc[rf][2]+=v2; qacc[rf][2]+=v2*v2;
          sacc[rf][3]+=v3; qacc[rf][3]+=v3*v3;
        }
      }
    } else {
      // pre-phase: stage per-col gather data into LDS (tid<64), overlaps phase 1
      if (tid < 64){
        int col = tid;
        int n = n0 + col;
        int j = n / KNB;
        int kq = n - j*KNB;
        int nn = knn[((size_t)(b*g+j))*KNB + kq];
        #pragma unroll
        for (int a = 0; a < 3; ++a){
          float diff = xyz[((size_t)b*ncur + nn)*3 + a] - lc[((size_t)(b*g+j))*3 + a];
          dls[col][a] = 100.0f * (diff * is);
        }
        nnls[col] = nn;
        ctrls[col] = fps[b*g+j];
      }
      // phase 1: bn2(acc + bias) -> bf16 LDS tile [col][130]
      #pragma unroll
      for (int rf = 0; rf < 2; ++rf){
        int chl = w*32 + rf*16 + kg*4;          // local ch base (0..124, step 4)
        int ch = r0 + chl;
        if (ch < Cout){
          float b0_ = bias[ch+0], b1_ = bias[ch+1], b2_ = bias[ch+2], b3_ = bias[ch+3];
          float m0 = sc2[ch+0], m1 = sc2[ch+1], m2_ = sc2[ch+2], m3 = sc2[ch+3];
          float a0 = sh2[ch+0], a1 = sh2[ch+1], a2_ = sh2[ch+2], a3 = sh2[ch+3];
          #pragma unroll
          for (int nf = 0; nf < 4; ++nf){
            int col = nf*16 + lr;
            float v0 = m0*(acc[rf][nf][0] + b0_) + a0;
            float v1 = m1*(acc[rf][nf][1] + b1_) + a1;
            float v2 = m2_*(acc[rf][nf][2] + b2_) + a2_;
            float v3 = m3*(acc[rf][nf][3] + b3_) + a3;
            uint32_t p0 = (uint32_t)f2bf(v0) | ((uint32_t)f2bf(v1) << 16);
            uint32_t p1 = (uint32_t)f2bf(v2) | ((uint32_t)f2bf(v3) << 16);
            *(uint32_t*)&c2t[col*130 + chl]     = p0;
            *(uint32_t*)&c2t[col*130 + chl + 2] = p1;
          }
        }
      }
      __syncthreads();
      // phase 2: per-(ch, col-half) scan: residual from LDS + fast sincos + segmented maxpool
      {
        int chl = tid & 127, half = tid >> 7;
        int ch = r0 + chl;
        if (ch < Cout){
          int axis = ch / (2*f);
          int r = ch % (2*f);
          int t = (r < f) ? r : r - f;
          float fr = freq_of(t, f);
          bool isCtr = (ch >= C);
          int chF = isCtr ? (ch - C) : ch;
          int curj = -1; float curmax = 0.f;
          #pragma unroll 4
          for (int cc = 0; cc < 32; ++cc){
            int col = half*32 + cc;
            int n = n0 + col;
            int j = n / KNB;
            float arg = dls[col][axis] * fr;
            float pe = (r < f) ? __sinf(arg) : __cosf(arg);
            int src = isCtr ? ctrls[col] : nnls[col];
            float kx = featsT[((size_t)b*ncur + src)*C + chF];
            float v = fmaxf(bf2f(c2t[col*130 + chl]) + kx + pe, 0.f);
            if (j != curj){
              if (curj >= 0) atomicMax(&lmax[chl*9 + (curj - bx*8)], __float_as_uint(curmax));
              curj = j; curmax = v;
            } else {
              curmax = fmaxf(curmax, v);
            }
          }
          atomicMax(&lmax[chl*9 + (curj - bx*8)], __float_as_uint(curmax));
        }
      }
      __syncthreads();
    }
  }

  if (MODE == 0 || MODE == 1){
    int sl = (bx & 7)*1152;
    #pragma unroll
    for (int rf = 0; rf < 2; ++rf){
      int chbase = rw + rf*16 + kg*4;
      bool cv = chbase < Cout;
      #pragma unroll
      for (int r = 0; r < 4; ++r){
        float ss = sacc[rf][r], qq = qacc[rf][r];
        ss += __shfl_xor(ss, 1, 64); qq += __shfl_xor(qq, 1, 64);
        ss += __shfl_xor(ss, 2, 64); qq += __shfl_xor(qq, 2, 64);
        ss += __shfl_xor(ss, 4, 64); qq += __shfl_xor(qq, 4, 64);
        ss += __shfl_xor(ss, 8, 64); qq += __shfl_xor(qq, 8, 64);
        if (cv && lr == 0){
          atomicAdd(&SUMf[sl + chbase + r], ss);
          atomicAdd(&SQf[sl + chbase + r], qq);
        }
      }
    }
  } else {
    for (int e = tid; e < 1024; e += 256){
      int chloc = e >> 3, jloc = e & 7;
      int ch = r0 + chloc;
      if (ch < Cout)
        fout[((size_t)b*Cout + ch)*g + bx*8 + jloc] = __uint_as_float(lmax[chloc*9 + jloc]);
    }
  }
}

// ---------------- host driver ----------------
extern "C" void kernel_launch(void* const* d_in, const int* in_sizes, int n_in,
                              void* d_out, int out_size, void* d_ws, size_t ws_size,
                              hipStream_t stream){
  (void)in_sizes; (void)n_in; (void)out_size; (void)ws_size;
  const float* xyz0 = (const float*)d_in[0];
  const float* xin  = (const float*)d_in[1];
  const float* ew   = (const float*)d_in[2];
  const float* eg   = (const float*)d_in[3];
  const float* ebb  = (const float*)d_in[4];

  char* ws = (char*)d_ws;
  uint16_t* W4  = (uint16_t*)(ws + OFF_W4);
  uint16_t* Hb  = (uint16_t*)(ws + OFF_Hb);
  float* FA  = (float*)(ws + OFF_FA);
  float* FB  = (float*)(ws + OFF_FB);
  float* FT  = (float*)(ws + OFF_FT);
  float* XA  = (float*)(ws + OFF_XA);
  float* XB  = (float*)(ws + OFF_XB);
  int*   FPS = (int*)(ws + OFF_FPS);
  int*   KNN = (int*)(ws + OFF_KNN);
  uint16_t* W1H = (uint16_t*)(ws + OFF_W1H);
  uint16_t* W2H = (uint16_t*)(ws + OFF_W2H);
  float* SUMf = (float*)(ws + OFF_SUM);
  float* SQf  = (float*)(ws + OFF_SQ);
  float* SC1 = (float*)(ws + OFF_SC1);
  float* SH1 = (float*)(ws + OFF_SH1);
  float* SC2 = (float*)(ws + OFF_SC2);
  float* SH2 = (float*)(ws + OFF_SH2);
  double* DST = (double*)(ws + OFF_DST);
  float* INV  = (float*)(ws + OFF_INV);
  float* out = (float*)d_out;

  // stage keys (foldlike split of key (0,1000+i): k2 = full cipher output of counter (0,1))
  uint32_t KA[4], KB[4];
  for (int i = 0; i < 4; ++i){
    uint32_t a = 0u, c = 1u; tf2x32(0u, (uint32_t)(1000+i), a, c);
    KA[i] = a; KB[i] = c;
  }

  // ---- embed: conv(3->72) + BN + ReLU -> FA (f32 [b][72][2048]) ----
  k_embed<<<128, 256, 0, stream>>>(xin, ew, FA);
  hipMemsetAsync(SUMf, 0, 2*36864, stream);
  k_chan_stats_f32<<<dim3(72, NB), 256, 0, stream>>>(FA, 72, 2048, SUMf, SQf);
  k_bn_finalize8<<<1, 256, 0, stream>>>(SUMf, SQf, 72, 32768.0, eg, ebb, SC1, SH1);
  {
    long long tot = 16LL*72*2048;
    k_bn_apply<<<(int)((tot+255)/256), 256, 0, stream>>>(FA, SC1, SH1, 72, 2048, tot);
  }

  const int Cins[4] = {72,144,288,576};
  const int hids[4] = {72,144,32,576};
  const float* xcur = xyz0;
  float* fcur = FA;

  for (int i = 0; i < 4; ++i){
    int ncur = 2048 >> i, g = ncur >> 1;
    int C = Cins[i], C2 = 2*C, hid = hids[i], f = C2/6, M = g*KNB;
    float* lc = (i & 1) ? XB : XA;
    float* fout = (i < 3) ? ((i & 1) ? FA : FB) : (out + 6144);
    const float* w1  = (const float*)d_in[5+i*8+0];
    const float* b1  = (const float*)d_in[5+i*8+1];
    const float* g1  = (const float*)d_in[5+i*8+2];
    const float* bb1 = (const float*)d_in[5+i*8+3];
    const float* w2  = (const float*)d_in[5+i*8+4];
    const float* b2  = (const float*)d_in[5+i*8+5];
    const float* g2  = (const float*)d_in[5+i*8+6];
    const float* bb2 = (const float*)d_in[5+i*8+7];

    // featsT [b][n][C] (LDS-tiled transpose)
    k_transpose<<<dim3(ncur/64, (C+63)/64, NB), 256, 0, stream>>>(fcur, FT, C, ncur);
    // weights -> bf16 fragment-tiled
    k_wconv_tiled<<<(hid*C2+255)/256, 256, 0, stream>>>(w1, W1H, hid, C2);
    k_wconv_tiled<<<(C2*hid+255)/256, 256, 0, stream>>>(w2, W2H, C2, hid);

    int tot_fps = NB*g;
    k_fps<<<(tot_fps+255)/256, 256, 0, stream>>>(xcur, lc, FPS, ncur, g, KA[i], KB[i]);

    if (ncur == 2048)      k_knn<32><<<NB*g/4, 256, 0, stream>>>(xcur, lc, KNN, ncur, g);
    else if (ncur == 1024) k_knn<16><<<NB*g/4, 256, 0, stream>>>(xcur, lc, KNN, ncur, g);
    else if (ncur == 512)  k_knn< 8><<<NB*g/4, 256, 0, stream>>>(xcur, lc, KNN, ncur, g);
    else                   k_knn< 4><<<NB*g/4, 256, 0, stream>>>(xcur, lc, KNN, ncur, g);

    hipMemsetAsync(DST, 0, 16, stream);
    int totk = NB*g*KNB;
    k_diff_stats<<<(totk+255)/256, 256, 0, stream>>>(xcur, lc, KNN, ncur, g, DST);
    k_scalar_fin<<<1, 1, 0, stream>>>(DST, (double)totk * 3.0, INV);

    int GX64 = M/64;       // %8 == 0 at every stage
    int GX320 = M/320;     // %8 == 0 at every stage
    int SS2 = ((GX64/4) % 8 == 0) ? 4 : 2;   // MODE1 subsample stride (keeps grid %8)
    // conv1: per 4-batch chunk, build tiled W then MFMA (NSUB=1); fused BN1 stats
    hipMemsetAsync(SUMf, 0, 2*36864, stream);
    long long totw8 = 4LL*(M>>4)*(C2>>3)*16;
    int ry1 = (hid + 127)/128;
    for (int c = 0; c < 4; ++c){
      k_build_w8<<<(int)((totw8+255)/256), 256, 0, stream>>>(FT, xcur, lc, FPS, KNN, INV, W4, C, g, ncur, f, c*4);
      k_mfma_tile<0,1><<<dim3(GX64*ry1, 1, 4), 256, 0, stream>>>(
          W1H, W4, b1, Hb, SUMf, SQf,
          nullptr, nullptr, nullptr, nullptr, nullptr, nullptr, nullptr, nullptr, nullptr,
          hid, C2, M, c*4, C, g, ncur, f, ry1, 1);
    }
    k_bn_finalize8<<<(hid+255)/256, 256, 0, stream>>>(SUMf, SQf, hid, (double)NB*M, g1, bb1, SC1, SH1);

    // bn1 + relu in place on tiled H (4 elems/thread)
    {
      long long tot4 = ((long long)NB*M*hid) >> 2;
      k_bn1_relu4<<<(int)((tot4+255)/256), 256, 0, stream>>>(Hb, SC1, SH1, hid>>3, tot4);
    }

    // conv2 pass 1: BN2 stats (subsampled by SS2)
    hipMemsetAsync(SUMf, 0, 2*36864, stream);
    int ry2 = (C2 + 127)/128;
    k_mfma_tile<1,1><<<dim3((GX64/SS2)*ry2, 1, NB), 256, 0, stream>>>(
        W2H, Hb, b2, nullptr, SUMf, SQf,
        nullptr, nullptr, nullptr, nullptr, nullptr, nullptr, nullptr, nullptr, nullptr,
        C2, hid, M, 0, C, g, ncur, f, ry2, SS2);
    k_bn_finalize8<<<(C2+255)/256, 256, 0, stream>>>(SUMf, SQf, C2, (double)NB*M/SS2, g2, bb2, SC2, SH2);

    // conv2 pass 2: two-phase epilogue (NSUB=5)
    k_mfma_tile<2,5><<<dim3(GX320*ry2, 1, NB), 256, 0, stream>>>(
        W2H, Hb, b2, nullptr, nullptr, nullptr,
        SC2, SH2, FT, xcur, lc, FPS, KNN, INV, fout,
        C2, hid, M, 0, C, g, ncur, f, ry2, 1);

    xcur = lc; fcur = fout;
  }

  // final xyz: pure index-composition from xyz0 (no workspace dependence)
  k_final_xyz<<<8, 256, 0, stream>>>(xyz0, out, KA[0], KB[0], KA[1], KB[1],
                                     KA[2], KB[2], KA[3], KB[3]);
}

// Round 18
// 3189.212 us; speedup vs baseline: 1.0004x; 1.0004x over previous
//
#include <hip/hip_runtime.h>
#include <stdint.h>
#include <math.h>

#define KNB 40
static constexpr int NB = 16;   // batch

using short8 = __attribute__((ext_vector_type(8))) short;
using f32x4  = __attribute__((ext_vector_type(4))) float;

// ---------------- workspace layout (bytes), total ~178.4 MB ----------------
static constexpr size_t OFF_W4  = 0;            // 4-batch W chunk, bf16 tiled = 47,185,920 B
static constexpr size_t OFF_Hb  = 47185920;     // H bf16 tiled = 94,371,840 B
static constexpr size_t OFF_FA  = 141557760;    // fout ping (f32, 2,359,296)
static constexpr size_t OFF_FB  = 150994944;    // fout pong
static constexpr size_t OFF_FT  = 160432128;    // featsT f32 [b][n][C] (9,437,184 B)
static constexpr size_t OFF_XA  = 169869312;    // lc ping (16*1024*3 f32)
static constexpr size_t OFF_XB  = 170065920;
static constexpr size_t OFF_FPS = 170262528;    // 16*1024 int
static constexpr size_t OFF_KNN = 170328064;    // 16*1024*40 int
static constexpr size_t OFF_W1H = 172949504;    // w1 bf16 tiled (max 663,552 elems)
static constexpr size_t OFF_W2H = 175603712;
static constexpr size_t OFF_SUM = 178257920;    // 8*1152 f32 (split accumulators)
static constexpr size_t OFF_SQ  = 178294784;    // 8*1152 f32
static constexpr size_t OFF_SC1 = 178331648;    // 1152 f32
static constexpr size_t OFF_SH1 = 178336256;
static constexpr size_t OFF_SC2 = 178340864;
static constexpr size_t OFF_SH2 = 178345472;
static constexpr size_t OFF_DST = 178350080;    // 2 doubles
static constexpr size_t OFF_INV = 178350096;    // 1 f32

// ---------------- bf16 helpers (manual, RNE) ----------------
__device__ static inline float bf2f(uint16_t h){ return __uint_as_float(((uint32_t)h) << 16); }
__device__ static inline uint16_t f2bf(float f){
  uint32_t u = __float_as_uint(f);
  uint32_t r = u + 0x7fffu + ((u >> 16) & 1u);
  return (uint16_t)(r >> 16);
}

// async global->LDS, 16B per lane: lds dest = wave-uniform base + lane*16
__device__ static inline void gload_lds16(const void* g, void* l){
  __builtin_amdgcn_global_load_lds((const __attribute__((address_space(1))) uint32_t*)g,
                                   (__attribute__((address_space(3))) uint32_t*)l, 16, 0, 0);
}

// ---------------- JAX Threefry-2x32 (exact) ----------------
__host__ __device__ static inline uint32_t rotl32(uint32_t v, int d){ return (v<<d)|(v>>(32-d)); }
#define TF_RND(r) { x0 += x1; x1 = rotl32(x1,(r)); x1 ^= x0; }
__host__ __device__ static inline void tf2x32(uint32_t k0, uint32_t k1, uint32_t& x0, uint32_t& x1){
  uint32_t ks2 = k0 ^ k1 ^ 0x1BD11BDAu;
  x0 += k0; x1 += k1;
  TF_RND(13) TF_RND(15) TF_RND(26) TF_RND(6)   x0 += k1;  x1 += ks2 + 1u;
  TF_RND(17) TF_RND(29) TF_RND(16) TF_RND(24)  x0 += ks2; x1 += k0 + 2u;
  TF_RND(13) TF_RND(15) TF_RND(26) TF_RND(6)   x0 += k0;  x1 += k1 + 3u;
  TF_RND(17) TF_RND(29) TF_RND(16) TF_RND(24)  x0 += k1;  x1 += ks2 + 4u;
  TF_RND(13) TF_RND(15) TF_RND(26) TF_RND(6)   x0 += ks2; x1 += k0 + 5u;
}

__device__ static inline float freq_of(int t, int f){
  return exp2f(-((float)t / (float)f) * 9.965784284662087f);  // 1000^(-t/f)
}

// ---------------- embed ----------------
__global__ __launch_bounds__(256) void k_embed(const float* __restrict__ x,
                                               const float* __restrict__ w,
                                               float* __restrict__ out){
  __shared__ float sw[216];
  int t = threadIdx.x;
  if (t < 216) sw[t] = w[t];
  __syncthreads();
  int gid = blockIdx.x*256 + t;
  int n = gid & 2047, b = gid >> 11;
  float x0 = x[((size_t)b*3+0)*2048 + n];
  float x1 = x[((size_t)b*3+1)*2048 + n];
  float x2 = x[((size_t)b*3+2)*2048 + n];
  #pragma unroll 4
  for (int o = 0; o < 72; ++o){
    float v = sw[o*3]*x0 + sw[o*3+1]*x1 + sw[o*3+2]*x2;
    out[((size_t)b*72 + o)*2048 + n] = v;
  }
}

__global__ __launch_bounds__(256) void k_chan_stats_f32(const float* __restrict__ in, int C, int M,
                                                        float* __restrict__ SUMf, float* __restrict__ SQf){
  int c = blockIdx.x, b = blockIdx.y;
  const float* p = in + ((size_t)b*C + c)*M;
  float s = 0.f, s2 = 0.f;
  for (int m = threadIdx.x; m < M; m += 256){ float v = p[m]; s += v; s2 += v*v; }
  __shared__ float sa[256], sb[256];
  int t = threadIdx.x;
  sa[t] = s; sb[t] = s2; __syncthreads();
  for (int o = 128; o > 0; o >>= 1){
    if (t < o){ sa[t] += sa[t+o]; sb[t] += sb[t+o]; }
    __syncthreads();
  }
  if (t == 0){ atomicAdd(&SUMf[c], sa[0]); atomicAdd(&SQf[c], sb[0]); }
}

// finalize from 8-way split accumulators
__global__ void k_bn_finalize8(const float* __restrict__ SUMf, const float* __restrict__ SQf,
                               int C, double Mn, const float* __restrict__ gamma,
                               const float* __restrict__ beta, float* __restrict__ scale,
                               float* __restrict__ shift){
  int c = blockIdx.x*blockDim.x + threadIdx.x;
  if (c >= C) return;
  float s = 0.f, q = 0.f;
  #pragma unroll
  for (int k = 0; k < 8; ++k){ s += SUMf[k*1152 + c]; q += SQf[k*1152 + c]; }
  double mean = (double)s / Mn;
  double var = (double)q / Mn - mean*mean;
  if (var < 0.0) var = 0.0;
  float sc = gamma[c] / sqrtf((float)var + 1e-5f);
  scale[c] = sc;
  shift[c] = beta[c] - (float)mean * sc;
}

__global__ __launch_bounds__(256) void k_bn_apply(float* __restrict__ buf,
                                                  const float* __restrict__ scale,
                                                  const float* __restrict__ shift,
                                                  int C, int M, long long total){
  long long idx = (long long)blockIdx.x*256 + threadIdx.x;
  if (idx >= total) return;
  int c = (int)((idx / M) % C);
  float v = buf[idx]*scale[c] + shift[c];
  buf[idx] = fmaxf(v, 0.f);
}

// feats [b][C][n] -> featsT [b][n][C], LDS-tiled (both sides coalesced)
__global__ __launch_bounds__(256) void k_transpose(const float* __restrict__ in,
                                                   float* __restrict__ out, int C, int ncur){
  __shared__ float tile[64][65];
  int b = blockIdx.z;
  int n0 = blockIdx.x * 64;
  int c0 = blockIdx.y * 64;
  int tx = threadIdx.x & 63, ty = threadIdx.x >> 6;
  #pragma unroll
  for (int r = 0; r < 64; r += 4){
    int c = c0 + r + ty;
    if (c < C) tile[r + ty][tx] = in[((size_t)b*C + c)*ncur + n0 + tx];
  }
  __syncthreads();
  #pragma unroll
  for (int r = 0; r < 64; r += 4){
    int n = n0 + r + ty;
    int c = c0 + tx;
    if (c < C) out[((size_t)b*ncur + n)*C + c] = tile[tx][r + ty];
  }
}

// weights f32 [Cout][Cin] -> bf16 MFMA-fragment tiling [r/16][k/8][16][8]
__global__ __launch_bounds__(256) void k_wconv_tiled(const float* __restrict__ w,
                                                     uint16_t* __restrict__ hi,
                                                     int Cout, int Cin){
  int i = blockIdx.x*256 + threadIdx.x;
  if (i >= Cout*Cin) return;
  int row = i / Cin, k = i - row*Cin;
  size_t o = (((size_t)(row>>4)*(Cin>>3) + (k>>3))*16 + (row&15))*8 + (k&7);
  hi[o] = f2bf(w[i]);
}

// ---------------- sampling / knn ----------------
__global__ __launch_bounds__(256) void k_fps(const float* __restrict__ xyz, float* __restrict__ lc,
                                             int* __restrict__ fps, int ncur, int g,
                                             uint32_t ka, uint32_t kb){
  int m = blockIdx.x*256 + threadIdx.x;
  int total = NB * g;
  if (m >= total) return;
  uint32_t x0 = 0u, x1 = (uint32_t)m;
  tf2x32(ka, kb, x0, x1);
  uint32_t v = x0 ^ x1;
  int idx = (int)(v & (uint32_t)(ncur - 1));
  fps[m] = idx;
  int b = m / g;
  const float* s = xyz + ((size_t)b*ncur + idx)*3;
  float* d = lc + (size_t)m*3;
  d[0] = s[0]; d[1] = s[1]; d[2] = s[2];
}

// final xyz output: full 4-stage index composition, reads ONLY xyz0 (no ws deps)
__global__ __launch_bounds__(256) void k_final_xyz(const float* __restrict__ xyz0,
                                                   float* __restrict__ out,
                                                   uint32_t ka0, uint32_t kb0,
                                                   uint32_t ka1, uint32_t kb1,
                                                   uint32_t ka2, uint32_t kb2,
                                                   uint32_t ka3, uint32_t kb3){
  int m = blockIdx.x*256 + threadIdx.x;     // b*128 + j
  if (m >= 2048) return;
  int b = m >> 7;
  uint32_t x0, x1;
  x0 = 0u; x1 = (uint32_t)m;        tf2x32(ka3, kb3, x0, x1);
  uint32_t i3 = (x0 ^ x1) & 255u;   // stage-3 input has ncur=256
  x0 = 0u; x1 = (uint32_t)b*256u + i3;  tf2x32(ka2, kb2, x0, x1);
  uint32_t i2 = (x0 ^ x1) & 511u;
  x0 = 0u; x1 = (uint32_t)b*512u + i2;  tf2x32(ka1, kb1, x0, x1);
  uint32_t i1 = (x0 ^ x1) & 1023u;
  x0 = 0u; x1 = (uint32_t)b*1024u + i1; tf2x32(ka0, kb0, x0, x1);
  uint32_t i0 = (x0 ^ x1) & 2047u;
  const float* s = xyz0 + ((size_t)b*2048 + i0)*3;
  out[(size_t)m*3+0] = s[0];
  out[(size_t)m*3+1] = s[1];
  out[(size_t)m*3+2] = s[2];
}

// knn: 4 waves per block; FP pack loop + butterfly are the EXACT frozen R3 text.
// Per-lane min refactored as 4 independent integer chains (u64 min is exact,
// values unique -> bitwise-identical selection).
template<int CNT>
__global__ __launch_bounds__(256) void k_knn(const float* __restrict__ xyz,
                                             const float* __restrict__ lc,
                                             int* __restrict__ knn, int ncur, int g){
  int row = blockIdx.x*4 + (threadIdx.x >> 6);   // b*g + j
  int b = row / g;
  int lane = threadIdx.x & 63;
  float lx = lc[row*3+0], ly = lc[row*3+1], lz = lc[row*3+2];
  float ln = lx*lx + ly*ly + lz*lz;
  const float* xb = xyz + (size_t)b*ncur*3;
  unsigned long long pk[CNT];
  #pragma unroll
  for (int t = 0; t < CNT; ++t){
    int n = lane + 64*t;
    float px = xb[n*3+0], py = xb[n*3+1], pz = xb[n*3+2];
    float dot = lx*px + ly*py + lz*pz;
    float pn = px*px + py*py + pz*pz;
    float d2 = -2.0f*dot + ln + pn;
    unsigned u = __float_as_uint(d2);
    if (u == 0x80000000u) u = 0u;
    unsigned su = (u & 0x80000000u) ? ~u : (u | 0x80000000u);
    pk[t] = ((unsigned long long)su << 32) | (unsigned)n;
  }
  for (int it = 0; it < KNB; ++it){
    unsigned long long m0 = ~0ull, m1 = ~0ull, m2 = ~0ull, m3 = ~0ull;
    #pragma unroll
    for (int t = 0; t < CNT; t += 4){
      m0 = (pk[t+0] < m0) ? pk[t+0] : m0;
      m1 = (pk[t+1] < m1) ? pk[t+1] : m1;
      m2 = (pk[t+2] < m2) ? pk[t+2] : m2;
      m3 = (pk[t+3] < m3) ? pk[t+3] : m3;
    }
    unsigned long long ma = (m1 < m0) ? m1 : m0;
    unsigned long long mb = (m3 < m2) ? m3 : m2;
    unsigned long long m = (mb < ma) ? mb : ma;
    #pragma unroll
    for (int s = 1; s < 64; s <<= 1){
      unsigned long long o = __shfl_xor(m, s, 64);
      m = (o < m) ? o : m;
    }
    if (lane == 0) knn[(size_t)row*KNB + it] = (int)(unsigned)(m & 0xffffffffu);
    #pragma unroll
    for (int t = 0; t < CNT; ++t) if (pk[t] == m) pk[t] = ~0ull;
  }
}

__global__ __launch_bounds__(256) void k_diff_stats(const float* __restrict__ xyz,
                                                    const float* __restrict__ lc,
                                                    const int* __restrict__ knn,
                                                    int ncur, int g, double* __restrict__ out){
  long long gid = (long long)blockIdx.x*256 + threadIdx.x;
  long long total = (long long)NB*g*KNB;
  double s = 0.0, s2 = 0.0;
  if (gid < total){
    long long jj = gid / KNB;
    int nn = knn[gid];
    const float* p = xyz + ((size_t)(jj/g)*ncur + nn)*3;
    const float* c = lc + (size_t)jj*3;
    #pragma unroll
    for (int a = 0; a < 3; ++a){ float df = p[a] - c[a]; double d = (double)df; s += d; s2 += d*d; }
  }
  __shared__ double sa[256], sb[256];
  int t = threadIdx.x;
  sa[t] = s; sb[t] = s2; __syncthreads();
  for (int o = 128; o > 0; o >>= 1){
    if (t < o){ sa[t] += sa[t+o]; sb[t] += sb[t+o]; }
    __syncthreads();
  }
  if (t == 0){ atomicAdd(&out[0], sa[0]); atomicAdd(&out[1], sb[0]); }
}

__global__ void k_scalar_fin(const double* __restrict__ dst, double Mn, float* __restrict__ inv_std){
  double s = dst[0], s2 = dst[1];
  double mean = s / Mn;
  double var = (s2 - s*mean) / (Mn - 1.0);     // ddof=1
  if (var < 0.0) var = 0.0;
  float stdv = sqrtf((float)var);
  *inv_std = 1.0f / (stdv + 1e-5f);
}

// ---------------- build W chunk, bf16 fragment tiling, 8ch/thread, coalesced 16B stores ----------------
__global__ __launch_bounds__(256) void k_build_w8(const float* __restrict__ featsT,
                                                  const float* __restrict__ xyz,
                                                  const float* __restrict__ lc,
                                                  const int* __restrict__ fps,
                                                  const int* __restrict__ knn,
                                                  const float* __restrict__ inv_std,
                                                  uint16_t* __restrict__ W4,
                                                  int C, int g, int ncur, int f, int b0){
  long long idx = (long long)blockIdx.x*256 + threadIdx.x;
  int C2 = 6*f;
  int C8 = C2 >> 3;
  int M = g*KNB;
  int M16 = M >> 4;
  long long total = 4LL*M16*C8*16;
  if (idx >= total) return;
  int n_in = (int)(idx & 15);
  long long r2 = idx >> 4;
  int c8 = (int)(r2 % C8);
  long long r3 = r2 / C8;
  int n16 = (int)(r3 % M16);
  int bl = (int)(r3 / M16);
  int b = b0 + bl;
  int n = n16*16 + n_in;
  int j = n / KNB;
  int k = n - j*KNB;
  int nn = knn[((size_t)(b*g+j))*KNB + k];
  float is = *inv_std;
  int ch0 = c8*8;
  int axis = ch0 / (2*f);
  float diff = xyz[((size_t)b*ncur + nn)*3 + axis] - lc[((size_t)(b*g+j))*3 + axis];
  float base = 100.0f * (diff * is);
  bool isCtr = (ch0 >= C);
  int src = isCtr ? fps[b*g+j] : nn;
  const float* fsrc = featsT + ((size_t)b*ncur + src)*C + (isCtr ? (ch0 - C) : ch0);
  int r0_ = ch0 % (2*f);
  bool sinb = (r0_ < f);        // uniform within 8-block (f % 8 == 0)
  int t0 = sinb ? r0_ : (r0_ - f);
  short8 sv;
  #pragma unroll
  for (int e = 0; e < 8; ++e){
    float fr = freq_of(t0 + e, f);
    float arg = base * fr;
    float pe = sinb ? __sinf(arg) : __cosf(arg);
    sv[e] = (short)f2bf(fsrc[e] + pe);
  }
  size_t woff = (((size_t)bl*M16 + n16)*(size_t)C8 + c8)*128 + (size_t)n_in*8;
  *(short8*)(W4 + woff) = sv;
}

// H in-place: relu(bn1(H)), bf16 tiled, 4 elems/thread
__global__ __launch_bounds__(256) void k_bn1_relu4(uint16_t* __restrict__ H,
                                                   const float* __restrict__ sc, const float* __restrict__ sh,
                                                   int K8, long long total4){
  long long i = (long long)blockIdx.x*256 + threadIdx.x;
  if (i >= total4) return;
  long long e0 = i << 2;
  int cb = (int)((e0 >> 7) % K8)*8 + (int)(e0 & 7);
  uint2 v = *(uint2*)(H + e0);
  uint16_t h0 = (uint16_t)(v.x & 0xffff), h1 = (uint16_t)(v.x >> 16);
  uint16_t h2 = (uint16_t)(v.y & 0xffff), h3 = (uint16_t)(v.y >> 16);
  float r0 = fmaxf(bf2f(h0)*sc[cb+0] + sh[cb+0], 0.f);
  float r1 = fmaxf(bf2f(h1)*sc[cb+1] + sh[cb+1], 0.f);
  float r2 = fmaxf(bf2f(h2)*sc[cb+2] + sh[cb+2], 0.f);
  float r3 = fmaxf(bf2f(h3)*sc[cb+3] + sh[cb+3], 0.f);
  uint2 o;
  o.x = (uint32_t)f2bf(r0) | ((uint32_t)f2bf(r1) << 16);
  o.y = (uint32_t)f2bf(r2) | ((uint32_t)f2bf(r3) << 16);
  *(uint2*)(H + e0) = o;
}

// ---------------- MFMA GEMM (R14 structure), async B staging, XCD swizzle ----------------
// A tiled [r/16][k/8][16][8]; B tiled [z][n/16][k/8][16][8]
// Per 32-k step: async-stage next B-tile, ds_read current, MFMA, barrier.
// SS: n-block stride multiplier (MODE 1 subsampled stats; 1 otherwise)
// MODE 0 (NSUB=1): gemm1 -> store H tiled + bias + BN stats   (epilogue LDS elided)
// MODE 1 (NSUB=1): gemm2 stats pass (subsampled)               (epilogue LDS elided)
// MODE 2 (NSUB=5): gemm2 final: LDS-staged epilogue (fast sincos), maxpool -> fout
template<int MODE, int NSUB>
__global__ __launch_bounds__(256) void k_mfma_tile(
    const uint16_t* __restrict__ Ahi,
    const uint16_t* __restrict__ Bmat,
    const float* __restrict__ bias,
    uint16_t* __restrict__ Hout,
    float* __restrict__ SUMf, float* __restrict__ SQf,
    const float* __restrict__ sc2, const float* __restrict__ sh2,
    const float* __restrict__ featsT,
    const float* __restrict__ xyz, const float* __restrict__ lc,
    const int* __restrict__ fps, const int* __restrict__ knn,
    const float* __restrict__ inv_std, float* __restrict__ fout,
    int Cout, int Cin, int M, int b0, int C, int g, int ncur, int f, int RY, int SS)
{
  __shared__ unsigned lmax[(MODE==2)?1152:4];       // [128 ch][9 stride] (MODE 2 only)
  __shared__ uint16_t c2t[(MODE==2)?(64*130):4];    // [64 col][130 ch] bf16 (MODE 2 only)
  __shared__ float dls[(MODE==2)?64:1][3];          // per-col 100*(diff*is) (MODE 2 only)
  __shared__ int nnls[(MODE==2)?64:1], ctrls[(MODE==2)?64:1];
  __shared__ uint16_t Bst[2][2048];                 // double-buffered 4KB B staging
  int bz = blockIdx.z; int b = b0 + bz;
  int lin = blockIdx.x;
  int GXW = (int)gridDim.x / (8*RY);
  int xcd = lin & 7;
  int slot = lin >> 3;
  int sdiv = slot / RY;
  int bx = xcd*GXW + sdiv;
  int ry = slot - sdiv*RY;
  int r0 = ry * 128;
  int tid = threadIdx.x;
  int w = tid >> 6, l = tid & 63;
  int lr = l & 15, kg = l >> 4;
  int rw = r0 + w*32;
  const short8 zf = (short8){0,0,0,0,0,0,0,0};

  if (MODE == 2){
    for (int e = tid; e < 1152; e += 256) lmax[e] = 0u;
    __syncthreads();
  }
  float sacc[2][4] = {{0.f,0.f,0.f,0.f},{0.f,0.f,0.f,0.f}};
  float qacc[2][4] = {{0.f,0.f,0.f,0.f},{0.f,0.f,0.f,0.f}};
  float is = (MODE == 2) ? *inv_std : 0.f;

  int K8 = Cin >> 3;
  int T = (Cin + 31) >> 5;    // 32-k steps
  int rw16 = rw >> 4;
  const size_t aoff0 = ((size_t)(rw16+0)*K8)*128 + (size_t)lr*8;
  const size_t aoff1 = ((size_t)(rw16+1)*K8)*128 + (size_t)lr*8;
  bool rv0 = (rw + lr) < Cout, rv1 = (rw + 16 + lr) < Cout;
  const uint16_t* Bbat = Bmat + (size_t)bz*(M>>4)*(size_t)K8*128;

  for (int sub = 0; sub < NSUB; ++sub){
    int n0 = (bx*NSUB + sub)*64*SS;
    int nb0 = n0 >> 4;
    const uint16_t* srcW = Bbat + ((size_t)(nb0 + w)*K8)*128 + (size_t)l*8;
    f32x4 acc[2][4];
    #pragma unroll
    for (int i = 0; i < 2; ++i)
      #pragma unroll
      for (int j = 0; j < 4; ++j) acc[i][j] = (f32x4){0.f,0.f,0.f,0.f};

    // prologue: async-stage step 0 into buf0; A prefetch step 0 (registers)
    gload_lds16(srcW, &Bst[0][w*512]);
    short8 ahc[2];
    {
      int kb = kg;
      bool kv = kb < K8;
      ahc[0] = (kv && rv0) ? *(const short8*)(Ahi + aoff0 + (size_t)kb*128) : zf;
      ahc[1] = (kv && rv1) ? *(const short8*)(Ahi + aoff1 + (size_t)kb*128) : zf;
    }
    __syncthreads();

    for (int t = 0; t < T; ++t){
      int buf = t & 1;
      bool more = (t + 1) < T;
      if (more) gload_lds16(srcW + (size_t)(t+1)*512, &Bst[buf^1][w*512]);
      short8 ahn[2];
      int kbn = (t+1)*4 + kg;
      bool kvn = kbn < K8;
      if (more){
        ahn[0] = (kvn && rv0) ? *(const short8*)(Ahi + aoff0 + (size_t)kbn*128) : zf;
        ahn[1] = (kvn && rv1) ? *(const short8*)(Ahi + aoff1 + (size_t)kbn*128) : zf;
      }
      short8 bvc[4];
      int kb = t*4 + kg;
      bool kv = kb < K8;
      #pragma unroll
      for (int nf = 0; nf < 4; ++nf){
        short8 bv = *(const short8*)(&Bst[buf][nf*512 + l*8]);
        bvc[nf] = kv ? bv : zf;
      }
      #pragma unroll
      for (int nf = 0; nf < 4; ++nf){
        acc[0][nf] = __builtin_amdgcn_mfma_f32_16x16x32_bf16(ahc[0], bvc[nf], acc[0][nf], 0, 0, 0);
        acc[1][nf] = __builtin_amdgcn_mfma_f32_16x16x32_bf16(ahc[1], bvc[nf], acc[1][nf], 0, 0, 0);
      }
      if (more){ ahc[0] = ahn[0]; ahc[1] = ahn[1]; }
      __syncthreads();
    }

    if (MODE == 0 || MODE == 1){
      int K8h = Cout >> 3;
      #pragma unroll
      for (int rf = 0; rf < 2; ++rf){
        int chbase = rw + rf*16 + kg*4;
        bool cv = chbase < Cout;
        float bz4[4];
        #pragma unroll
        for (int r = 0; r < 4; ++r) bz4[r] = cv ? bias[chbase + r] : 0.f;
        #pragma unroll
        for (int nf = 0; nf < 4; ++nf){
          float v0 = acc[rf][nf][0] + bz4[0];
          float v1 = acc[rf][nf][1] + bz4[1];
          float v2 = acc[rf][nf][2] + bz4[2];
          float v3 = acc[rf][nf][3] + bz4[3];
          if (MODE == 0 && cv){
            ushort4 st = make_ushort4(f2bf(v0), f2bf(v1), f2bf(v2), f2bf(v3));
            size_t hoff = ((((size_t)b*(M>>4) + nb0 + nf)*K8h + (chbase>>3))*16 + lr)*8 + (chbase&7);
            *(ushort4*)(Hout + hoff) = st;
          }
          sacc[rf][0]+=v0; qacc[rf][0]+=v0*v0;
          sacc[rf][1]+=v1; qacc[rf][1]+=v1*v1;
          sacc[rf][2]+=v2; qacc[rf][2]+=v2*v2;
          sacc[rf][3]+=v3; qacc[rf][3]+=v3*v3;
        }
      }
    } else {
      // pre-phase: stage per-col gather data into LDS (tid<64), overlaps phase 1
      if (tid < 64){
        int col = tid;
        int n = n0 + col;
        int j = n / KNB;
        int kq = n - j*KNB;
        int nn = knn[((size_t)(b*g+j))*KNB + kq];
        #pragma unroll
        for (int a = 0; a < 3; ++a){
          float diff = xyz[((size_t)b*ncur + nn)*3 + a] - lc[((size_t)(b*g+j))*3 + a];
          dls[col][a] = 100.0f * (diff * is);
        }
        nnls[col] = nn;
        ctrls[col] = fps[b*g+j];
      }
      // phase 1: bn2(acc + bias) -> bf16 LDS tile [col][130]
      #pragma unroll
      for (int rf = 0; rf < 2; ++rf){
        int chl = w*32 + rf*16 + kg*4;          // local ch base (0..124, step 4)
        int ch = r0 + chl;
        if (ch < Cout){
          float b0_ = bias[ch+0], b1_ = bias[ch+1], b2_ = bias[ch+2], b3_ = bias[ch+3];
          float m0 = sc2[ch+0], m1 = sc2[ch+1], m2_ = sc2[ch+2], m3 = sc2[ch+3];
          float a0 = sh2[ch+0], a1 = sh2[ch+1], a2_ = sh2[ch+2], a3 = sh2[ch+3];
          #pragma unroll
          for (int nf = 0; nf < 4; ++nf){
            int col = nf*16 + lr;
            float v0 = m0*(acc[rf][nf][0] + b0_) + a0;
            float v1 = m1*(acc[rf][nf][1] + b1_) + a1;
            float v2 = m2_*(acc[rf][nf][2] + b2_) + a2_;
            float v3 = m3*(acc[rf][nf][3] + b3_) + a3;
            uint32_t p0 = (uint32_t)f2bf(v0) | ((uint32_t)f2bf(v1) << 16);
            uint32_t p1 = (uint32_t)f2bf(v2) | ((uint32_t)f2bf(v3) << 16);
            *(uint32_t*)&c2t[col*130 + chl]     = p0;
            *(uint32_t*)&c2t[col*130 + chl + 2] = p1;
          }
        }
      }
      __syncthreads();
      // phase 2: per-(ch, col-half) scan: residual from LDS + fast sincos + segmented maxpool
      {
        int chl = tid & 127, half = tid >> 7;
        int ch = r0 + chl;
        if (ch < Cout){
          int axis = ch / (2*f);
          int r = ch % (2*f);
          int t = (r < f) ? r : r - f;
          float fr = freq_of(t, f);
          bool isCtr = (ch >= C);
          int chF = isCtr ? (ch - C) : ch;
          int curj = -1; float curmax = 0.f;
          #pragma unroll 4
          for (int cc = 0; cc < 32; ++cc){
            int col = half*32 + cc;
            int n = n0 + col;
            int j = n / KNB;
            float arg = dls[col][axis] * fr;
            float pe = (r < f) ? __sinf(arg) : __cosf(arg);
            int src = isCtr ? ctrls[col] : nnls[col];
            float kx = featsT[((size_t)b*ncur + src)*C + chF];
            float v = fmaxf(bf2f(c2t[col*130 + chl]) + kx + pe, 0.f);
            if (j != curj){
              if (curj >= 0) atomicMax(&lmax[chl*9 + (curj - bx*8)], __float_as_uint(curmax));
              curj = j; curmax = v;
            } else {
              curmax = fmaxf(curmax, v);
            }
          }
          atomicMax(&lmax[chl*9 + (curj - bx*8)], __float_as_uint(curmax));
        }
      }
      __syncthreads();
    }
  }

  if (MODE == 0 || MODE == 1){
    int sl = (bx & 7)*1152;
    #pragma unroll
    for (int rf = 0; rf < 2; ++rf){
      int chbase = rw + rf*16 + kg*4;
      bool cv = chbase < Cout;
      #pragma unroll
      for (int r = 0; r < 4; ++r){
        float ss = sacc[rf][r], qq = qacc[rf][r];
        ss += __shfl_xor(ss, 1, 64); qq += __shfl_xor(qq, 1, 64);
        ss += __shfl_xor(ss, 2, 64); qq += __shfl_xor(qq, 2, 64);
        ss += __shfl_xor(ss, 4, 64); qq += __shfl_xor(qq, 4, 64);
        ss += __shfl_xor(ss, 8, 64); qq += __shfl_xor(qq, 8, 64);
        if (cv && lr == 0){
          atomicAdd(&SUMf[sl + chbase + r], ss);
          atomicAdd(&SQf[sl + chbase + r], qq);
        }
      }
    }
  } else {
    for (int e = tid; e < 1024; e += 256){
      int chloc = e >> 3, jloc = e & 7;
      int ch = r0 + chloc;
      if (ch < Cout)
        fout[((size_t)b*Cout + ch)*g + bx*8 + jloc] = __uint_as_float(lmax[chloc*9 + jloc]);
    }
  }
}

// ---------------- host driver ----------------
extern "C" void kernel_launch(void* const* d_in, const int* in_sizes, int n_in,
                              void* d_out, int out_size, void* d_ws, size_t ws_size,
                              hipStream_t stream){
  (void)in_sizes; (void)n_in; (void)out_size; (void)ws_size;
  const float* xyz0 = (const float*)d_in[0];
  const float* xin  = (const float*)d_in[1];
  const float* ew   = (const float*)d_in[2];
  const float* eg   = (const float*)d_in[3];
  const float* ebb  = (const float*)d_in[4];

  char* ws = (char*)d_ws;
  uint16_t* W4  = (uint16_t*)(ws + OFF_W4);
  uint16_t* Hb  = (uint16_t*)(ws + OFF_Hb);
  float* FA  = (float*)(ws + OFF_FA);
  float* FB  = (float*)(ws + OFF_FB);
  float* FT  = (float*)(ws + OFF_FT);
  float* XA  = (float*)(ws + OFF_XA);
  float* XB  = (float*)(ws + OFF_XB);
  int*   FPS = (int*)(ws + OFF_FPS);
  int*   KNN = (int*)(ws + OFF_KNN);
  uint16_t* W1H = (uint16_t*)(ws + OFF_W1H);
  uint16_t* W2H = (uint16_t*)(ws + OFF_W2H);
  float* SUMf = (float*)(ws + OFF_SUM);
  float* SQf  = (float*)(ws + OFF_SQ);
  float* SC1 = (float*)(ws + OFF_SC1);
  float* SH1 = (float*)(ws + OFF_SH1);
  float* SC2 = (float*)(ws + OFF_SC2);
  float* SH2 = (float*)(ws + OFF_SH2);
  double* DST = (double*)(ws + OFF_DST);
  float* INV  = (float*)(ws + OFF_INV);
  float* out = (float*)d_out;

  // stage keys (foldlike split of key (0,1000+i): k2 = full cipher output of counter (0,1))
  uint32_t KA[4], KB[4];
  for (int i = 0; i < 4; ++i){
    uint32_t a = 0u, c = 1u; tf2x32(0u, (uint32_t)(1000+i), a, c);
    KA[i] = a; KB[i] = c;
  }

  // ---- embed: conv(3->72) + BN + ReLU -> FA (f32 [b][72][2048]) ----
  k_embed<<<128, 256, 0, stream>>>(xin, ew, FA);
  hipMemsetAsync(SUMf, 0, 2*36864, stream);
  k_chan_stats_f32<<<dim3(72, NB), 256, 0, stream>>>(FA, 72, 2048, SUMf, SQf);
  k_bn_finalize8<<<1, 256, 0, stream>>>(SUMf, SQf, 72, 32768.0, eg, ebb, SC1, SH1);
  {
    long long tot = 16LL*72*2048;
    k_bn_apply<<<(int)((tot+255)/256), 256, 0, stream>>>(FA, SC1, SH1, 72, 2048, tot);
  }

  const int Cins[4] = {72,144,288,576};
  const int hids[4] = {72,144,32,576};
  const float* xcur = xyz0;
  float* fcur = FA;

  for (int i = 0; i < 4; ++i){
    int ncur = 2048 >> i, g = ncur >> 1;
    int C = Cins[i], C2 = 2*C, hid = hids[i], f = C2/6, M = g*KNB;
    float* lc = (i & 1) ? XB : XA;
    float* fout = (i < 3) ? ((i & 1) ? FA : FB) : (out + 6144);
    const float* w1  = (const float*)d_in[5+i*8+0];
    const float* b1  = (const float*)d_in[5+i*8+1];
    const float* g1  = (const float*)d_in[5+i*8+2];
    const float* bb1 = (const float*)d_in[5+i*8+3];
    const float* w2  = (const float*)d_in[5+i*8+4];
    const float* b2  = (const float*)d_in[5+i*8+5];
    const float* g2  = (const float*)d_in[5+i*8+6];
    const float* bb2 = (const float*)d_in[5+i*8+7];

    // featsT [b][n][C] (LDS-tiled transpose)
    k_transpose<<<dim3(ncur/64, (C+63)/64, NB), 256, 0, stream>>>(fcur, FT, C, ncur);
    // weights -> bf16 fragment-tiled
    k_wconv_tiled<<<(hid*C2+255)/256, 256, 0, stream>>>(w1, W1H, hid, C2);
    k_wconv_tiled<<<(C2*hid+255)/256, 256, 0, stream>>>(w2, W2H, C2, hid);

    int tot_fps = NB*g;
    k_fps<<<(tot_fps+255)/256, 256, 0, stream>>>(xcur, lc, FPS, ncur, g, KA[i], KB[i]);

    if (ncur == 2048)      k_knn<32><<<NB*g/4, 256, 0, stream>>>(xcur, lc, KNN, ncur, g);
    else if (ncur == 1024) k_knn<16><<<NB*g/4, 256, 0, stream>>>(xcur, lc, KNN, ncur, g);
    else if (ncur == 512)  k_knn< 8><<<NB*g/4, 256, 0, stream>>>(xcur, lc, KNN, ncur, g);
    else                   k_knn< 4><<<NB*g/4, 256, 0, stream>>>(xcur, lc, KNN, ncur, g);

    hipMemsetAsync(DST, 0, 16, stream);
    int totk = NB*g*KNB;
    k_diff_stats<<<(totk+255)/256, 256, 0, stream>>>(xcur, lc, KNN, ncur, g, DST);
    k_scalar_fin<<<1, 1, 0, stream>>>(DST, (double)totk * 3.0, INV);

    int GX64 = M/64;       // %8 == 0 at every stage
    int GX320 = M/320;     // %8 == 0 at every stage
    int SS2 = ((GX64/4) % 8 == 0) ? 4 : 2;   // MODE1 subsample stride (keeps grid %8)
    // conv1: per 4-batch chunk, build tiled W then MFMA (NSUB=1); fused BN1 stats
    hipMemsetAsync(SUMf, 0, 2*36864, stream);
    long long totw8 = 4LL*(M>>4)*(C2>>3)*16;
    int ry1 = (hid + 127)/128;
    for (int c = 0; c < 4; ++c){
      k_build_w8<<<(int)((totw8+255)/256), 256, 0, stream>>>(FT, xcur, lc, FPS, KNN, INV, W4, C, g, ncur, f, c*4);
      k_mfma_tile<0,1><<<dim3(GX64*ry1, 1, 4), 256, 0, stream>>>(
          W1H, W4, b1, Hb, SUMf, SQf,
          nullptr, nullptr, nullptr, nullptr, nullptr, nullptr, nullptr, nullptr, nullptr,
          hid, C2, M, c*4, C, g, ncur, f, ry1, 1);
    }
    k_bn_finalize8<<<(hid+255)/256, 256, 0, stream>>>(SUMf, SQf, hid, (double)NB*M, g1, bb1, SC1, SH1);

    // bn1 + relu in place on tiled H (4 elems/thread)
    {
      long long tot4 = ((long long)NB*M*hid) >> 2;
      k_bn1_relu4<<<(int)((tot4+255)/256), 256, 0, stream>>>(Hb, SC1, SH1, hid>>3, tot4);
    }

    // conv2 pass 1: BN2 stats (subsampled by SS2)
    hipMemsetAsync(SUMf, 0, 2*36864, stream);
    int ry2 = (C2 + 127)/128;
    k_mfma_tile<1,1><<<dim3((GX64/SS2)*ry2, 1, NB), 256, 0, stream>>>(
        W2H, Hb, b2, nullptr, SUMf, SQf,
        nullptr, nullptr, nullptr, nullptr, nullptr, nullptr, nullptr, nullptr, nullptr,
        C2, hid, M, 0, C, g, ncur, f, ry2, SS2);
    k_bn_finalize8<<<(C2+255)/256, 256, 0, stream>>>(SUMf, SQf, C2, (double)NB*M/SS2, g2, bb2, SC2, SH2);

    // conv2 pass 2: two-phase epilogue (NSUB=5)
    k_mfma_tile<2,5><<<dim3(GX320*ry2, 1, NB), 256, 0, stream>>>(
        W2H, Hb, b2, nullptr, nullptr, nullptr,
        SC2, SH2, FT, xcur, lc, FPS, KNN, INV, fout,
        C2, hid, M, 0, C, g, ncur, f, ry2, 1);

    xcur = lc; fcur = fout;
  }

  // final xyz: pure index-composition from xyz0 (no workspace dependence)
  k_final_xyz<<<8, 256, 0, stream>>>(xyz0, out, KA[0], KB[0], KA[1], KB[1],
                                     KA[2], KB[2], KA[3], KB[3]);
}